// Round 2
// baseline (832.549 us; speedup 1.0000x reference)
//
#include <hip/hip_runtime.h>
#include <hip/hip_bf16.h>

typedef __bf16 bf16x8 __attribute__((ext_vector_type(8)));
typedef float  f32x4  __attribute__((ext_vector_type(4)));

#define LQ   1024
#define HQ   32
#define HKV  8
#define GRP  4
#define DH   128
#define CHK  512
#define KB   32
// scale * log2(e) folded into Q so softmax runs in exp2 domain
#define QSCALE (0.08838834764831845f * 1.44269504088896341f)
#define MASKVAL (-3.0e38f)

// LDS map: K tile [32][128] bf16 @0 (8 KB, swizzled), V^T [128][32] bf16 @8192 (8 KB, swizzled),
//          per-wave P [16][32] bf16 @16384 + w*1024 (4 KB total)
__global__ __launch_bounds__(256, 2)
void zz_attn(const float* __restrict__ qg, const float* __restrict__ kg,
             const float* __restrict__ vg, float* __restrict__ outg)
{
    __shared__ __align__(16) char lds[20480];
    const int bid    = blockIdx.x;
    const int q_tile = bid & 63;
    const int hkv    = bid >> 6;
    const int tid    = threadIdx.x;
    const int w      = tid >> 6;
    const int lane   = tid & 63;
    const int l16    = lane & 15;
    const int lhi    = lane >> 4;
    const int h      = hkv * GRP + w;     // q head for this wave
    const int qr0    = q_tile << 4;       // q-row base (0..1023)
    const int half   = q_tile >> 5;       // 0: chunk 3, 1: chunk 12
    const int qrel0  = (q_tile & 31) << 4; // base position within chunk

    // ---- Q fragments in registers (scale folded), assumed k-map: k = lhi*8 + j
    bf16x8 qf[4];
    {
        const float* qp = qg + ((qr0 + l16) * HQ + h) * DH + lhi * 8;
        #pragma unroll
        for (int kb = 0; kb < 4; ++kb) {
            f32x4 t0 = *(const f32x4*)(qp + kb * 32);
            f32x4 t1 = *(const f32x4*)(qp + kb * 32 + 4);
            bf16x8 f;
            #pragma unroll
            for (int j = 0; j < 4; ++j) {
                f[j]     = (__bf16)(t0[j] * QSCALE);
                f[j + 4] = (__bf16)(t1[j] * QSCALE);
            }
            qf[kb] = f;
        }
    }

    f32x4 acc[8];
    #pragma unroll
    for (int i = 0; i < 8; ++i) acc[i] = f32x4{0.f, 0.f, 0.f, 0.f};
    float m_r[4], l_r[4];
    #pragma unroll
    for (int r = 0; r < 4; ++r) { m_r[r] = -1e30f; l_r[r] = 0.f; }

    char* const pbase = lds + 16384 + w * 1024;

    auto do_tile = [&](int krow, int cbase, bool masked) {
        __syncthreads();   // previous tile's LDS reads done before overwrite
        {   // ---- stage 32 keys: K row-major + V transposed, bf16, XOR-swizzled
            const int key = tid >> 3;
            const int d0  = (tid & 7) << 4;
            const float* kp = kg + ((krow + key) * HKV + hkv) * DH + d0;
            const float* vp = vg + ((krow + key) * HKV + hkv) * DH + d0;
            f32x4 a0 = *(const f32x4*)(kp);
            f32x4 a1 = *(const f32x4*)(kp + 4);
            f32x4 a2 = *(const f32x4*)(kp + 8);
            f32x4 a3 = *(const f32x4*)(kp + 12);
            bf16x8 b0, b1;
            #pragma unroll
            for (int j = 0; j < 4; ++j) {
                b0[j] = (__bf16)a0[j]; b0[j + 4] = (__bf16)a1[j];
                b1[j] = (__bf16)a2[j]; b1[j + 4] = (__bf16)a3[j];
            }
            const int kbyte = key * 256 + d0 * 2;
            const int ksw   = (key & 7) << 4;
            *(bf16x8*)(lds + ((kbyte)      ^ ksw)) = b0;
            *(bf16x8*)(lds + ((kbyte + 16) ^ ksw)) = b1;

            f32x4 c0 = *(const f32x4*)(vp);
            f32x4 c1 = *(const f32x4*)(vp + 4);
            f32x4 c2 = *(const f32x4*)(vp + 8);
            f32x4 c3 = *(const f32x4*)(vp + 12);
            #pragma unroll
            for (int i = 0; i < 16; ++i) {
                float fv = (i < 4) ? c0[i] : (i < 8) ? c1[i - 4]
                         : (i < 12) ? c2[i - 8] : c3[i - 12];
                const int d = d0 + i;
                const int vbyte = (d * 64 + key * 2) ^ ((d & 7) << 4);
                *(__bf16*)(lds + 8192 + vbyte) = (__bf16)fv;
            }
        }
        __syncthreads();

        // ---- S = Q·K^T  (D-layout: col=l16=key, row=lhi*4+r=q)
        f32x4 s0 = f32x4{0.f, 0.f, 0.f, 0.f};
        f32x4 s1 = f32x4{0.f, 0.f, 0.f, 0.f};
        #pragma unroll
        for (int kb = 0; kb < 4; ++kb) {
            const int dby = (kb * 32 + lhi * 8) * 2;
            bf16x8 k0 = *(const bf16x8*)(lds + ((l16 * 256 + dby)        ^ ((l16 & 7) << 4)));
            bf16x8 k1 = *(const bf16x8*)(lds + (((l16 + 16) * 256 + dby) ^ ((l16 & 7) << 4)));
            s0 = __builtin_amdgcn_mfma_f32_16x16x32_bf16(qf[kb], k0, s0, 0, 0, 0);
            s1 = __builtin_amdgcn_mfma_f32_16x16x32_bf16(qf[kb], k1, s1, 0, 0, 0);
        }

        if (masked) {   // zig-zag diagonal: key pos-in-chunk > q pos-in-chunk => hide
            #pragma unroll
            for (int r = 0; r < 4; ++r) {
                const int qrel = qrel0 + lhi * 4 + r;
                if (cbase + l16 > qrel)      s0[r] = MASKVAL;
                if (cbase + 16 + l16 > qrel) s1[r] = MASKVAL;
            }
        }

        // ---- online softmax (exp2 domain); row lives across 16 lanes of group lhi
        float pmax[4];
        #pragma unroll
        for (int r = 0; r < 4; ++r) pmax[r] = fmaxf(s0[r], s1[r]);
        #pragma unroll
        for (int off = 1; off < 16; off <<= 1) {
            #pragma unroll
            for (int r = 0; r < 4; ++r)
                pmax[r] = fmaxf(pmax[r], __shfl_xor(pmax[r], off));
        }

        f32x4 p0, p1;
        float alpha[4], rsum[4];
        #pragma unroll
        for (int r = 0; r < 4; ++r) {
            const float mnew = fmaxf(m_r[r], pmax[r]);
            alpha[r] = exp2f(m_r[r] - mnew);
            m_r[r]   = mnew;
            p0[r] = exp2f(s0[r] - mnew);
            p1[r] = exp2f(s1[r] - mnew);
            rsum[r] = p0[r] + p1[r];
        }
        #pragma unroll
        for (int off = 1; off < 16; off <<= 1) {
            #pragma unroll
            for (int r = 0; r < 4; ++r)
                rsum[r] += __shfl_xor(rsum[r], off);
        }
        #pragma unroll
        for (int r = 0; r < 4; ++r) l_r[r] = l_r[r] * alpha[r] + rsum[r];
        #pragma unroll
        for (int nb = 0; nb < 8; ++nb) {
            #pragma unroll
            for (int r = 0; r < 4; ++r) acc[nb][r] *= alpha[r];
        }

        // ---- P -> LDS (bf16, swizzled), re-read as A-frag (wave-local region)
        #pragma unroll
        for (int r = 0; r < 4; ++r) {
            const int rq  = lhi * 4 + r;
            const int rsw = (rq & 7) << 4;
            *(__bf16*)(pbase + ((rq * 64 + l16 * 2)        ^ rsw)) = (__bf16)p0[r];
            *(__bf16*)(pbase + ((rq * 64 + (l16 + 16) * 2) ^ rsw)) = (__bf16)p1[r];
        }
        bf16x8 pa = *(const bf16x8*)(pbase + ((l16 * 64 + lhi * 16) ^ ((l16 & 7) << 4)));
        #pragma unroll
        for (int nb = 0; nb < 8; ++nb) {
            const int d = nb * 16 + l16;
            bf16x8 vb = *(const bf16x8*)(lds + 8192 + ((d * 64 + lhi * 16) ^ ((d & 7) << 4)));
            acc[nb] = __builtin_amdgcn_mfma_f32_16x16x32_bf16(pa, vb, acc[nb], 0, 0, 0);
        }
    };

    // ---- static zig-zag visibility for RANK=3 (chunks 3 and 12)
    const unsigned int fullmask = half ? 0xFF55u : 0x0015u;
    const int diag_slot = half ? 7 : 6;

    #pragma unroll 1
    for (int s = 0; s < 16; ++s) {
        if (!((fullmask >> s) & 1)) continue;
        #pragma unroll 1
        for (int t = 0; t < 16; ++t)
            do_tile(s * CHK + t * KB, 0, false);
    }
    const int nd = (qrel0 >> 5) + 1;   // diagonal tiles needed for this q-tile
    #pragma unroll 1
    for (int t = 0; t < nd; ++t)
        do_tile(diag_slot * CHK + t * KB, t * KB, true);

    // ---- epilogue: normalize and store fp32
    #pragma unroll
    for (int r = 0; r < 4; ++r) l_r[r] = 1.0f / l_r[r];
    float* op = outg + (qr0 + lhi * 4) * (HQ * DH) + h * DH + l16;
    #pragma unroll
    for (int nb = 0; nb < 8; ++nb) {
        #pragma unroll
        for (int r = 0; r < 4; ++r)
            op[r * (HQ * DH) + nb * 16] = acc[nb][r] * l_r[r];
    }
}

extern "C" void kernel_launch(void* const* d_in, const int* in_sizes, int n_in,
                              void* d_out, int out_size, void* d_ws, size_t ws_size,
                              hipStream_t stream)
{
    (void)in_sizes; (void)n_in; (void)out_size; (void)d_ws; (void)ws_size;
    const float* q = (const float*)d_in[0];
    const float* k = (const float*)d_in[1];
    const float* v = (const float*)d_in[2];
    float* out = (float*)d_out;
    dim3 grid(512), block(256);
    hipLaunchKernelGGL(zz_attn, grid, block, 0, stream, q, k, v, out);
}

// Round 3
// 448.922 us; speedup vs baseline: 1.8545x; 1.8545x over previous
//
#include <hip/hip_runtime.h>
#include <hip/hip_bf16.h>

typedef __bf16 bf16x8 __attribute__((ext_vector_type(8)));
typedef float  f32x4  __attribute__((ext_vector_type(4)));

#define LQ   1024
#define HQ   32
#define HKV  8
#define GRP  4
#define DH   128
#define CHK  512
#define KB   32
#define RHN  (LQ * HQ)        // 32768 row-heads
#define NSPLIT 4
// scale * log2(e) folded into Q so softmax runs in exp2 domain
#define QSCALE (0.08838834764831845f * 1.44269504088896341f)
#define MASKVAL (-3.0e38f)

// LDS map: K tile [32][128] bf16 @0 (8 KB, swizzled), V^T [128][32] bf16 @8192 (8 KB, swizzled),
//          per-wave P [16][32] bf16 @16384 + w*1024 (4 KB total)

// One 32-key tile: stage K + V^T to LDS, QK^T MFMA, online softmax, PV MFMA.
__device__ __forceinline__ void attn_tile(
    char* __restrict__ lds, char* __restrict__ pbase,
    const float* __restrict__ kg, const float* __restrict__ vg,
    int hkv, int krow, int cbase, bool masked,
    int tid, int l16, int lhi, int qrel0,
    const bf16x8 (&qf)[4], f32x4 (&acc)[8], float (&m_r)[4], float (&l_r)[4])
{
    __syncthreads();   // previous tile's LDS reads done before overwrite
    {   // ---- stage 32 keys: K row-major + V transposed, bf16, XOR-swizzled
        const int key = tid >> 3;
        const int d0  = (tid & 7) << 4;
        const float* kp = kg + ((krow + key) * HKV + hkv) * DH + d0;
        const float* vp = vg + ((krow + key) * HKV + hkv) * DH + d0;
        f32x4 a0 = *(const f32x4*)(kp);
        f32x4 a1 = *(const f32x4*)(kp + 4);
        f32x4 a2 = *(const f32x4*)(kp + 8);
        f32x4 a3 = *(const f32x4*)(kp + 12);
        bf16x8 b0, b1;
        #pragma unroll
        for (int j = 0; j < 4; ++j) {
            b0[j] = (__bf16)a0[j]; b0[j + 4] = (__bf16)a1[j];
            b1[j] = (__bf16)a2[j]; b1[j + 4] = (__bf16)a3[j];
        }
        const int kbyte = key * 256 + d0 * 2;
        const int ksw   = (key & 7) << 4;
        *(bf16x8*)(lds + ((kbyte)      ^ ksw)) = b0;
        *(bf16x8*)(lds + ((kbyte + 16) ^ ksw)) = b1;

        f32x4 c0 = *(const f32x4*)(vp);
        f32x4 c1 = *(const f32x4*)(vp + 4);
        f32x4 c2 = *(const f32x4*)(vp + 8);
        f32x4 c3 = *(const f32x4*)(vp + 12);
        #pragma unroll
        for (int i = 0; i < 16; ++i) {
            float fv = (i < 4) ? c0[i] : (i < 8) ? c1[i - 4]
                     : (i < 12) ? c2[i - 8] : c3[i - 12];
            const int d = d0 + i;
            // swizzle spreads the 8 d0-groups (stride-1024B) across 8 banks; 16B-granular
            const int vsw = ((d & 7) ^ ((d >> 4) & 7)) << 4;
            const int vbyte = (d * 64 + key * 2) ^ vsw;
            *(__bf16*)(lds + 8192 + vbyte) = (__bf16)fv;
        }
    }
    __syncthreads();

    // ---- S = Q·K^T  (D-layout: col=l16=key, row=lhi*4+r=q)
    f32x4 s0 = f32x4{0.f, 0.f, 0.f, 0.f};
    f32x4 s1 = f32x4{0.f, 0.f, 0.f, 0.f};
    __builtin_amdgcn_s_setprio(1);
    #pragma unroll
    for (int kb = 0; kb < 4; ++kb) {
        const int dby = (kb * 32 + lhi * 8) * 2;
        bf16x8 k0 = *(const bf16x8*)(lds + ((l16 * 256 + dby)        ^ ((l16 & 7) << 4)));
        bf16x8 k1 = *(const bf16x8*)(lds + (((l16 + 16) * 256 + dby) ^ ((l16 & 7) << 4)));
        s0 = __builtin_amdgcn_mfma_f32_16x16x32_bf16(qf[kb], k0, s0, 0, 0, 0);
        s1 = __builtin_amdgcn_mfma_f32_16x16x32_bf16(qf[kb], k1, s1, 0, 0, 0);
    }
    __builtin_amdgcn_s_setprio(0);

    if (masked) {   // zig-zag diagonal: key pos-in-chunk > q pos-in-chunk => hide
        #pragma unroll
        for (int r = 0; r < 4; ++r) {
            const int qrel = qrel0 + lhi * 4 + r;
            if (cbase + l16 > qrel)      s0[r] = MASKVAL;
            if (cbase + 16 + l16 > qrel) s1[r] = MASKVAL;
        }
    }

    // ---- online softmax (exp2 domain); row lives across 16 lanes of group lhi
    float pmax[4];
    #pragma unroll
    for (int r = 0; r < 4; ++r) pmax[r] = fmaxf(s0[r], s1[r]);
    #pragma unroll
    for (int off = 1; off < 16; off <<= 1) {
        #pragma unroll
        for (int r = 0; r < 4; ++r)
            pmax[r] = fmaxf(pmax[r], __shfl_xor(pmax[r], off));
    }

    f32x4 p0, p1;
    float alpha[4], rsum[4];
    #pragma unroll
    for (int r = 0; r < 4; ++r) {
        const float mnew = fmaxf(m_r[r], pmax[r]);
        alpha[r] = exp2f(m_r[r] - mnew);
        m_r[r]   = mnew;
        p0[r] = exp2f(s0[r] - mnew);
        p1[r] = exp2f(s1[r] - mnew);
        rsum[r] = p0[r] + p1[r];
    }
    #pragma unroll
    for (int off = 1; off < 16; off <<= 1) {
        #pragma unroll
        for (int r = 0; r < 4; ++r)
            rsum[r] += __shfl_xor(rsum[r], off);
    }
    #pragma unroll
    for (int r = 0; r < 4; ++r) l_r[r] = l_r[r] * alpha[r] + rsum[r];
    #pragma unroll
    for (int nb = 0; nb < 8; ++nb) {
        #pragma unroll
        for (int r = 0; r < 4; ++r) acc[nb][r] *= alpha[r];
    }

    // ---- P -> LDS (bf16, swizzled), re-read as A-frag (wave-local region)
    #pragma unroll
    for (int r = 0; r < 4; ++r) {
        const int rq  = lhi * 4 + r;
        const int rsw = (rq & 7) << 4;
        *(__bf16*)(pbase + ((rq * 64 + l16 * 2)        ^ rsw)) = (__bf16)p0[r];
        *(__bf16*)(pbase + ((rq * 64 + (l16 + 16) * 2) ^ rsw)) = (__bf16)p1[r];
    }
    bf16x8 pa = *(const bf16x8*)(pbase + ((l16 * 64 + lhi * 16) ^ ((l16 & 7) << 4)));
    __builtin_amdgcn_s_setprio(1);
    #pragma unroll
    for (int nb = 0; nb < 8; ++nb) {
        const int d = nb * 16 + l16;
        const int vsw = ((d & 7) ^ (nb & 7)) << 4;   // (d>>4)&7 == nb&7 here
        bf16x8 vb = *(const bf16x8*)(lds + 8192 + ((d * 64 + lhi * 16) ^ vsw));
        acc[nb] = __builtin_amdgcn_mfma_f32_16x16x32_bf16(pa, vb, acc[nb], 0, 0, 0);
    }
    __builtin_amdgcn_s_setprio(0);
}

__device__ __forceinline__ void load_qfrag(const float* __restrict__ qg,
                                           int qr0, int h, int l16, int lhi,
                                           bf16x8 (&qf)[4])
{
    const float* qp = qg + ((qr0 + l16) * HQ + h) * DH + lhi * 8;
    #pragma unroll
    for (int kb = 0; kb < 4; ++kb) {
        f32x4 t0 = *(const f32x4*)(qp + kb * 32);
        f32x4 t1 = *(const f32x4*)(qp + kb * 32 + 4);
        bf16x8 f;
        #pragma unroll
        for (int j = 0; j < 4; ++j) {
            f[j]     = (__bf16)(t0[j] * QSCALE);
            f[j + 4] = (__bf16)(t1[j] * QSCALE);
        }
        qf[kb] = f;
    }
}

// ---------------- split-KV kernel: 1280 blocks, writes unnormalized partials ----
__global__ __launch_bounds__(256, 2)
void zz_attn_part(const float* __restrict__ qg, const float* __restrict__ kg,
                  const float* __restrict__ vg,
                  float* __restrict__ Op, float* __restrict__ mp, float* __restrict__ lp)
{
    __shared__ __align__(16) char lds[20480];
    const int bid = blockIdx.x;
    int half, part, q_tile, hkv;
    if (bid < 256) { half = 0; part = 0; q_tile = bid & 31;              hkv = bid >> 5; }
    else { const int e = bid - 256; half = 1; part = e & 3;
           q_tile = 32 + ((e >> 2) & 31);                                hkv = e >> 7; }

    const int tid  = threadIdx.x;
    const int w    = tid >> 6;
    const int lane = tid & 63;
    const int l16  = lane & 15;
    const int lhi  = lane >> 4;
    const int h    = hkv * GRP + w;
    const int qr0  = q_tile << 4;
    const int qrel0 = (q_tile & 31) << 4;

    bf16x8 qf[4];
    load_qfrag(qg, qr0, h, l16, lhi, qf);

    f32x4 acc[8];
    #pragma unroll
    for (int i = 0; i < 8; ++i) acc[i] = f32x4{0.f, 0.f, 0.f, 0.f};
    float m_r[4], l_r[4];
    #pragma unroll
    for (int r = 0; r < 4; ++r) { m_r[r] = -1e30f; l_r[r] = 0.f; }

    char* const pbase = lds + 16384 + w * 1024;

    // slot sets (RANK=3: q-chunks 3 and 12; slot s holds chunk s/2 (even) or 15-s/2 (odd))
    unsigned fullmask;
    int diag_slot;
    if (half == 0) { fullmask = 0x0015u; diag_slot = 6; }
    else {
        fullmask = (part == 0) ? 0x0015u : (part == 1) ? 0x0340u
                 : (part == 2) ? 0x1C00u : 0xE000u;
        diag_slot = (part == 3) ? 7 : -1;
    }

    #pragma unroll 1
    for (int s = 0; s < 16; ++s) {
        if (!((fullmask >> s) & 1)) continue;
        #pragma unroll 1
        for (int t = 0; t < 16; ++t)
            attn_tile(lds, pbase, kg, vg, hkv, s * CHK + t * KB, 0, false,
                      tid, l16, lhi, qrel0, qf, acc, m_r, l_r);
    }
    if (diag_slot >= 0) {
        const int nd = (qrel0 >> 5) + 1;
        #pragma unroll 1
        for (int t = 0; t < nd; ++t)
            attn_tile(lds, pbase, kg, vg, hkv, diag_slot * CHK + t * KB, t * KB, true,
                      tid, l16, lhi, qrel0, qf, acc, m_r, l_r);
    }

    // ---- epilogue: write UNnormalized O~ + per-row m,l
    float* op = Op + (size_t)part * (LQ * HQ * DH) + ((qr0 + lhi * 4) * HQ + h) * DH + l16;
    #pragma unroll
    for (int nb = 0; nb < 8; ++nb) {
        #pragma unroll
        for (int r = 0; r < 4; ++r)
            op[r * (HQ * DH) + nb * 16] = acc[nb][r];
    }
    if (l16 == 0) {
        #pragma unroll
        for (int r = 0; r < 4; ++r) {
            const int rh = (qr0 + lhi * 4 + r) * HQ + h;
            mp[part * RHN + rh] = m_r[r];
            lp[part * RHN + rh] = l_r[r];
            if (half == 0) {   // rows of half-0 never get parts 1..3: neutralize
                #pragma unroll
                for (int s = 1; s < NSPLIT; ++s) {
                    mp[s * RHN + rh] = -1e30f;
                    lp[s * RHN + rh] = 0.f;
                }
            }
        }
    }
}

// ---------------- LSE-weighted combine ----------------
__global__ __launch_bounds__(256)
void zz_combine(const float* __restrict__ Op, const float* __restrict__ mp,
                const float* __restrict__ lp, float* __restrict__ outg)
{
    const int flat = blockIdx.x * 256 + threadIdx.x;   // one f32x4 per thread
    const int rh = flat >> 5;
    const int d4 = (flat & 31) << 2;
    const float m0 = mp[rh], m1 = mp[RHN + rh], m2 = mp[2 * RHN + rh], m3 = mp[3 * RHN + rh];
    const float M  = fmaxf(fmaxf(m0, m1), fmaxf(m2, m3));
    const float w0 = exp2f(m0 - M), w1 = exp2f(m1 - M), w2 = exp2f(m2 - M), w3 = exp2f(m3 - M);
    const float den = w0 * lp[rh] + w1 * lp[RHN + rh] + w2 * lp[2 * RHN + rh] + w3 * lp[3 * RHN + rh];
    const size_t base = (size_t)rh * DH + d4;
    f32x4 a0 = *(const f32x4*)(Op + base);
    f32x4 a1 = *(const f32x4*)(Op + (size_t)LQ * HQ * DH + base);
    f32x4 a2 = *(const f32x4*)(Op + (size_t)2 * LQ * HQ * DH + base);
    f32x4 a3 = *(const f32x4*)(Op + (size_t)3 * LQ * HQ * DH + base);
    f32x4 num = w0 * a0 + w1 * a1 + w2 * a2 + w3 * a3;
    const float inv = 1.0f / den;
    *(f32x4*)(outg + base) = num * inv;
}

// ---------------- fallback: proven round-2 mono kernel ----------------
__global__ __launch_bounds__(256, 2)
void zz_attn_mono(const float* __restrict__ qg, const float* __restrict__ kg,
                  const float* __restrict__ vg, float* __restrict__ outg)
{
    __shared__ __align__(16) char lds[20480];
    const int bid    = blockIdx.x;
    const int q_tile = bid & 63;
    const int hkv    = bid >> 6;
    const int tid    = threadIdx.x;
    const int w      = tid >> 6;
    const int lane   = tid & 63;
    const int l16    = lane & 15;
    const int lhi    = lane >> 4;
    const int h      = hkv * GRP + w;
    const int qr0    = q_tile << 4;
    const int half   = q_tile >> 5;
    const int qrel0  = (q_tile & 31) << 4;

    bf16x8 qf[4];
    load_qfrag(qg, qr0, h, l16, lhi, qf);

    f32x4 acc[8];
    #pragma unroll
    for (int i = 0; i < 8; ++i) acc[i] = f32x4{0.f, 0.f, 0.f, 0.f};
    float m_r[4], l_r[4];
    #pragma unroll
    for (int r = 0; r < 4; ++r) { m_r[r] = -1e30f; l_r[r] = 0.f; }

    char* const pbase = lds + 16384 + w * 1024;

    const unsigned int fullmask = half ? 0xFF55u : 0x0015u;
    const int diag_slot = half ? 7 : 6;

    #pragma unroll 1
    for (int s = 0; s < 16; ++s) {
        if (!((fullmask >> s) & 1)) continue;
        #pragma unroll 1
        for (int t = 0; t < 16; ++t)
            attn_tile(lds, pbase, kg, vg, hkv, s * CHK + t * KB, 0, false,
                      tid, l16, lhi, qrel0, qf, acc, m_r, l_r);
    }
    const int nd = (qrel0 >> 5) + 1;
    #pragma unroll 1
    for (int t = 0; t < nd; ++t)
        attn_tile(lds, pbase, kg, vg, hkv, diag_slot * CHK + t * KB, t * KB, true,
                  tid, l16, lhi, qrel0, qf, acc, m_r, l_r);

    #pragma unroll
    for (int r = 0; r < 4; ++r) l_r[r] = 1.0f / l_r[r];
    float* op = outg + (qr0 + lhi * 4) * (HQ * DH) + h * DH + l16;
    #pragma unroll
    for (int nb = 0; nb < 8; ++nb) {
        #pragma unroll
        for (int r = 0; r < 4; ++r)
            op[r * (HQ * DH) + nb * 16] = acc[nb][r] * l_r[r];
    }
}

extern "C" void kernel_launch(void* const* d_in, const int* in_sizes, int n_in,
                              void* d_out, int out_size, void* d_ws, size_t ws_size,
                              hipStream_t stream)
{
    (void)in_sizes; (void)n_in; (void)out_size;
    const float* q = (const float*)d_in[0];
    const float* k = (const float*)d_in[1];
    const float* v = (const float*)d_in[2];
    float* out = (float*)d_out;

    const size_t need = (size_t)NSPLIT * LQ * HQ * DH * 4   // O~ partials (64 MB)
                      + (size_t)2 * NSPLIT * RHN * 4;       // m, l (1 MB)
    if (ws_size >= need) {
        float* Op = (float*)d_ws;
        float* mp = Op + (size_t)NSPLIT * LQ * HQ * DH;
        float* lp = mp + (size_t)NSPLIT * RHN;
        hipLaunchKernelGGL(zz_attn_part, dim3(1280), dim3(256), 0, stream, q, k, v, Op, mp, lp);
        hipLaunchKernelGGL(zz_combine, dim3((RHN * DH / 4) / 256), dim3(256), 0, stream,
                           Op, mp, lp, out);
    } else {
        hipLaunchKernelGGL(zz_attn_mono, dim3(512), dim3(256), 0, stream, q, k, v, out);
    }
}

// Round 4
// 383.943 us; speedup vs baseline: 2.1684x; 1.1692x over previous
//
#include <hip/hip_runtime.h>
#include <hip/hip_bf16.h>

typedef __bf16 bf16x8 __attribute__((ext_vector_type(8)));
typedef float  f32x4  __attribute__((ext_vector_type(4)));

#define LQ   1024
#define HQ   32
#define HKV  8
#define GRP  4
#define DH   128
#define CHK  512
#define KB   32
#define RHN  (LQ * HQ)        // 32768 row-heads
#define NSPLIT 4
#define TILE_BYTES 8192
#define HKV_BYTES  (256 * TILE_BYTES)   // 256 tiles per head, 2 MB
// scale * log2(e) folded into Q so softmax runs in exp2 domain
#define QSCALE (0.08838834764831845f * 1.44269504088896341f)
#define MASKVAL (-3.0e38f)

typedef __attribute__((address_space(1))) const void gvoid_t;
typedef __attribute__((address_space(3))) void lvoid_t;
#define GLL(g, l) __builtin_amdgcn_global_load_lds((gvoid_t*)(g), (lvoid_t*)(l), 16, 0, 0)

__device__ __forceinline__ void load_qfrag(const float* __restrict__ qg,
                                           int qr0, int h, int l16, int lhi,
                                           bf16x8 (&qf)[4])
{
    const float* qp = qg + ((qr0 + l16) * HQ + h) * DH + lhi * 8;
    #pragma unroll
    for (int kb = 0; kb < 4; ++kb) {
        f32x4 t0 = *(const f32x4*)(qp + kb * 32);
        f32x4 t1 = *(const f32x4*)(qp + kb * 32 + 4);
        bf16x8 f;
        #pragma unroll
        for (int j = 0; j < 4; ++j) {
            f[j]     = (__bf16)(t0[j] * QSCALE);
            f[j + 4] = (__bf16)(t1[j] * QSCALE);
        }
        qf[kb] = f;
    }
}

// =============== prep: fp32 K/V -> bf16 LDS-image tiles in d_ws ===============
// K image (per 32-key tile, 8 KB): granule(key,dbg) at key*256 + ((dbg*16)^((key&7)<<4)),
//   content = K[row=tile*32+key][d=dbg*8 .. +7]
// V image (8 KB): granule(kg,d) at kg*2048 + d*16, content = V[row=tile*32+kg*8+j][d]
__global__ __launch_bounds__(256)
void zz_prep(const float* __restrict__ kg, const float* __restrict__ vg,
             char* __restrict__ Kp, char* __restrict__ Vp)
{
    const int bid  = blockIdx.x;
    const int hkv  = bid & 7;
    const int tile = bid >> 3;
    const int tid  = threadIdx.x;
    char* ko = Kp + (size_t)hkv * HKV_BYTES + (size_t)tile * TILE_BYTES;
    char* vo = Vp + (size_t)hkv * HKV_BYTES + (size_t)tile * TILE_BYTES;

    #pragma unroll
    for (int p = 0; p < 2; ++p) {   // K: 512 granules, 2 per thread
        const int gid = tid + p * 256;
        const int key = gid >> 4;
        const int dbg = gid & 15;
        const float* src = kg + ((size_t)(tile * 32 + key) * HKV + hkv) * DH + dbg * 8;
        f32x4 t0 = *(const f32x4*)src;
        f32x4 t1 = *(const f32x4*)(src + 4);
        bf16x8 b;
        #pragma unroll
        for (int j = 0; j < 4; ++j) { b[j] = (__bf16)t0[j]; b[j + 4] = (__bf16)t1[j]; }
        *(bf16x8*)(ko + key * 256 + ((dbg * 16) ^ ((key & 7) << 4))) = b;
    }
    #pragma unroll
    for (int p = 0; p < 2; ++p) {   // V: 512 granules, 2 per thread
        const int gid = tid + p * 256;
        const int d   = gid & 127;
        const int kg2 = (tid >> 7) + p * 2;
        bf16x8 b;
        #pragma unroll
        for (int j = 0; j < 8; ++j)
            b[j] = (__bf16)vg[((size_t)(tile * 32 + kg2 * 8 + j) * HKV + hkv) * DH + d];
        *(bf16x8*)(vo + kg2 * 2048 + d * 16) = b;
    }
}

// =============== main split-KV attention, global_load_lds + double buffer ====
// LDS: buf0 K@0 V@8192, buf1 K@16384 V@24576, per-wave P @32768 + w*1024
__global__ __launch_bounds__(256, 4)
void zz_part2(const float* __restrict__ qg, const char* __restrict__ Kp,
              const char* __restrict__ Vp,
              float* __restrict__ Op, float* __restrict__ mp, float* __restrict__ lp)
{
    __shared__ __align__(16) char lds[36864];
    const int bid = blockIdx.x;
    const int hkv = bid & 7;            // XCD-pinned: one KV head per XCD
    const int e   = bid >> 3;
    int half, part, q_tile;
    if (e < 32) { half = 0; part = 0; q_tile = e; }
    else { half = 1; part = (e - 32) >> 5; q_tile = 32 + ((e - 32) & 31); }

    const int tid  = threadIdx.x;
    const int w    = tid >> 6;
    const int lane = tid & 63;
    const int l16  = lane & 15;
    const int lhi  = lane >> 4;
    const int h    = hkv * GRP + w;
    const int qr0  = q_tile << 4;
    const int qrel0 = (q_tile & 31) << 4;

    bf16x8 qf[4];
    load_qfrag(qg, qr0, h, l16, lhi, qf);

    f32x4 acc[8];
    #pragma unroll
    for (int i = 0; i < 8; ++i) acc[i] = f32x4{0.f, 0.f, 0.f, 0.f};
    float m_r[4], l_r[4];
    #pragma unroll
    for (int r = 0; r < 4; ++r) { m_r[r] = -1e30f; l_r[r] = 0.f; }

    char* const pbase = lds + 32768 + w * 1024;

    // slot sets (RANK=3: q-chunks 3 and 12; slot s holds chunk s/2 (even) or 15-s/2 (odd))
    unsigned fullmask; int diag_slot;
    if (half == 0) { fullmask = 0x0015u; diag_slot = 6; }
    else {
        fullmask = (part == 0) ? 0x0015u : (part == 1) ? 0x0340u
                 : (part == 2) ? 0x1C00u : 0xE000u;
        diag_slot = (part == 3) ? 7 : -1;
    }
    const int nd = (diag_slot >= 0) ? ((qrel0 >> 5) + 1) : 0;

    // per-thread staged-source base (includes wave chunk + lane offset)
    const char* kpg = Kp + (size_t)hkv * HKV_BYTES + w * 2048 + lane * 16;
    const char* vpg = Vp + (size_t)hkv * HKV_BYTES + w * 2048 + lane * 16;

    auto stage = [&](int gt, int b) {
        const char* kt = kpg + (size_t)gt * TILE_BYTES;
        const char* vt = vpg + (size_t)gt * TILE_BYTES;
        char* kd = lds + b * 16384 + w * 2048;
        GLL(kt, kd); GLL(kt + 1024, kd + 1024);
        char* vd = kd + 8192;
        GLL(vt, vd); GLL(vt + 1024, vd + 1024);
    };
    auto gt_of = [&](unsigned rem, int t) {
        return rem ? ((int)(__builtin_ctz(rem) << 4) + t) : (diag_slot * 16 + t);
    };
    auto adv = [](unsigned& rem, int& t) {
        ++t; if (rem && t == 16) { rem &= rem - 1; t = 0; }
    };

    const int ksw16 = (l16 & 7) << 4;
    const int vlane = lhi * 2048 + l16 * 16;   // V image: granule(kg=lhi, d=nb*16+l16)

    unsigned remC = fullmask; int tC = 0;
    unsigned remN = remC;     int tN = 0; adv(remN, tN);
    stage(gt_of(remC, tC), 0);
    __syncthreads();
    int cur = 0;

    while (true) {
        const bool nv = (remN != 0) || (tN < nd);
        if (nv) stage(gt_of(remN, tN), cur ^ 1);

        // ---- compute tile (remC,tC) from buf[cur]
        char* kb_ = lds + cur * 16384;
        char* vb_ = kb_ + 8192;
        const bool masked = (remC == 0);
        const int  cbase  = masked ? (tC << 5) : 0;

        f32x4 s0 = f32x4{0.f, 0.f, 0.f, 0.f};
        f32x4 s1 = f32x4{0.f, 0.f, 0.f, 0.f};
        __builtin_amdgcn_s_setprio(1);
        #pragma unroll
        for (int kb = 0; kb < 4; ++kb) {
            const int dby = kb * 64 + lhi * 16;
            bf16x8 k0 = *(const bf16x8*)(kb_ + ((l16 * 256 + dby)        ^ ksw16));
            bf16x8 k1 = *(const bf16x8*)(kb_ + (((l16 + 16) * 256 + dby) ^ ksw16));
            s0 = __builtin_amdgcn_mfma_f32_16x16x32_bf16(qf[kb], k0, s0, 0, 0, 0);
            s1 = __builtin_amdgcn_mfma_f32_16x16x32_bf16(qf[kb], k1, s1, 0, 0, 0);
        }
        __builtin_amdgcn_s_setprio(0);

        if (masked) {
            #pragma unroll
            for (int r = 0; r < 4; ++r) {
                const int qrel = qrel0 + lhi * 4 + r;
                if (cbase + l16 > qrel)      s0[r] = MASKVAL;
                if (cbase + 16 + l16 > qrel) s1[r] = MASKVAL;
            }
        }

        float pmax[4];
        #pragma unroll
        for (int r = 0; r < 4; ++r) pmax[r] = fmaxf(s0[r], s1[r]);
        #pragma unroll
        for (int off = 1; off < 16; off <<= 1) {
            #pragma unroll
            for (int r = 0; r < 4; ++r)
                pmax[r] = fmaxf(pmax[r], __shfl_xor(pmax[r], off));
        }

        f32x4 p0, p1;
        float alpha[4], rsum[4];
        #pragma unroll
        for (int r = 0; r < 4; ++r) {
            const float mnew = fmaxf(m_r[r], pmax[r]);
            alpha[r] = exp2f(m_r[r] - mnew);
            m_r[r]   = mnew;
            p0[r] = exp2f(s0[r] - mnew);
            p1[r] = exp2f(s1[r] - mnew);
            rsum[r] = p0[r] + p1[r];
        }
        #pragma unroll
        for (int off = 1; off < 16; off <<= 1) {
            #pragma unroll
            for (int r = 0; r < 4; ++r)
                rsum[r] += __shfl_xor(rsum[r], off);
        }
        #pragma unroll
        for (int r = 0; r < 4; ++r) l_r[r] = l_r[r] * alpha[r] + rsum[r];
        #pragma unroll
        for (int nb = 0; nb < 8; ++nb) {
            #pragma unroll
            for (int r = 0; r < 4; ++r) acc[nb][r] *= alpha[r];
        }

        #pragma unroll
        for (int r = 0; r < 4; ++r) {
            const int rq  = lhi * 4 + r;
            const int rsw = (rq & 7) << 4;
            *(__bf16*)(pbase + ((rq * 64 + l16 * 2)        ^ rsw)) = (__bf16)p0[r];
            *(__bf16*)(pbase + ((rq * 64 + (l16 + 16) * 2) ^ rsw)) = (__bf16)p1[r];
        }
        bf16x8 pa = *(const bf16x8*)(pbase + ((l16 * 64 + lhi * 16) ^ ksw16));
        __builtin_amdgcn_s_setprio(1);
        #pragma unroll
        for (int nb = 0; nb < 8; ++nb) {
            bf16x8 vb = *(const bf16x8*)(vb_ + vlane + nb * 256);
            acc[nb] = __builtin_amdgcn_mfma_f32_16x16x32_bf16(pa, vb, acc[nb], 0, 0, 0);
        }
        __builtin_amdgcn_s_setprio(0);

        __syncthreads();
        if (!nv) break;
        cur ^= 1; remC = remN; tC = tN; adv(remN, tN);
    }

    // ---- epilogue: write UNnormalized O~ + per-row m,l
    float* op = Op + (size_t)part * (LQ * HQ * DH) + ((qr0 + lhi * 4) * HQ + h) * DH + l16;
    #pragma unroll
    for (int nb = 0; nb < 8; ++nb) {
        #pragma unroll
        for (int r = 0; r < 4; ++r)
            op[r * (HQ * DH) + nb * 16] = acc[nb][r];
    }
    if (l16 == 0) {
        #pragma unroll
        for (int r = 0; r < 4; ++r) {
            const int rh = (qr0 + lhi * 4 + r) * HQ + h;
            mp[part * RHN + rh] = m_r[r];
            lp[part * RHN + rh] = l_r[r];
            if (half == 0) {
                #pragma unroll
                for (int s = 1; s < NSPLIT; ++s) {
                    mp[s * RHN + rh] = -1e30f;
                    lp[s * RHN + rh] = 0.f;
                }
            }
        }
    }
}

// =============== LSE-weighted combine ===============
__global__ __launch_bounds__(256)
void zz_combine(const float* __restrict__ Op, const float* __restrict__ mp,
                const float* __restrict__ lp, float* __restrict__ outg)
{
    const int flat = blockIdx.x * 256 + threadIdx.x;
    const int rh = flat >> 5;
    const int d4 = (flat & 31) << 2;
    const float m0 = mp[rh], m1 = mp[RHN + rh], m2 = mp[2 * RHN + rh], m3 = mp[3 * RHN + rh];
    const float M  = fmaxf(fmaxf(m0, m1), fmaxf(m2, m3));
    const float w0 = exp2f(m0 - M), w1 = exp2f(m1 - M), w2 = exp2f(m2 - M), w3 = exp2f(m3 - M);
    const float den = w0 * lp[rh] + w1 * lp[RHN + rh] + w2 * lp[2 * RHN + rh] + w3 * lp[3 * RHN + rh];
    const size_t base = (size_t)rh * DH + d4;
    f32x4 a0 = *(const f32x4*)(Op + base);
    f32x4 a1 = *(const f32x4*)(Op + (size_t)LQ * HQ * DH + base);
    f32x4 a2 = *(const f32x4*)(Op + (size_t)2 * LQ * HQ * DH + base);
    f32x4 a3 = *(const f32x4*)(Op + (size_t)3 * LQ * HQ * DH + base);
    f32x4 num = w0 * a0 + w1 * a1 + w2 * a2 + w3 * a3;
    const float inv = 1.0f / den;
    *(f32x4*)(outg + base) = num * inv;
}

// =============== fallback: proven round-3 reg-staged tile ===============
__device__ __forceinline__ void attn_tile_f32(
    char* __restrict__ lds, char* __restrict__ pbase,
    const float* __restrict__ kg, const float* __restrict__ vg,
    int hkv, int krow, int cbase, bool masked,
    int tid, int l16, int lhi, int qrel0,
    const bf16x8 (&qf)[4], f32x4 (&acc)[8], float (&m_r)[4], float (&l_r)[4])
{
    __syncthreads();
    {
        const int key = tid >> 3;
        const int d0  = (tid & 7) << 4;
        const float* kp = kg + ((krow + key) * HKV + hkv) * DH + d0;
        const float* vp = vg + ((krow + key) * HKV + hkv) * DH + d0;
        f32x4 a0 = *(const f32x4*)(kp);
        f32x4 a1 = *(const f32x4*)(kp + 4);
        f32x4 a2 = *(const f32x4*)(kp + 8);
        f32x4 a3 = *(const f32x4*)(kp + 12);
        bf16x8 b0, b1;
        #pragma unroll
        for (int j = 0; j < 4; ++j) {
            b0[j] = (__bf16)a0[j]; b0[j + 4] = (__bf16)a1[j];
            b1[j] = (__bf16)a2[j]; b1[j + 4] = (__bf16)a3[j];
        }
        const int kbyte = key * 256 + d0 * 2;
        const int ksw   = (key & 7) << 4;
        *(bf16x8*)(lds + ((kbyte)      ^ ksw)) = b0;
        *(bf16x8*)(lds + ((kbyte + 16) ^ ksw)) = b1;

        f32x4 c0 = *(const f32x4*)(vp);
        f32x4 c1 = *(const f32x4*)(vp + 4);
        f32x4 c2 = *(const f32x4*)(vp + 8);
        f32x4 c3 = *(const f32x4*)(vp + 12);
        #pragma unroll
        for (int i = 0; i < 16; ++i) {
            float fv = (i < 4) ? c0[i] : (i < 8) ? c1[i - 4]
                     : (i < 12) ? c2[i - 8] : c3[i - 12];
            const int d = d0 + i;
            const int vsw = ((d & 7) ^ ((d >> 4) & 7)) << 4;
            const int vbyte = (d * 64 + key * 2) ^ vsw;
            *(__bf16*)(lds + 8192 + vbyte) = (__bf16)fv;
        }
    }
    __syncthreads();

    f32x4 s0 = f32x4{0.f, 0.f, 0.f, 0.f};
    f32x4 s1 = f32x4{0.f, 0.f, 0.f, 0.f};
    #pragma unroll
    for (int kb = 0; kb < 4; ++kb) {
        const int dby = (kb * 32 + lhi * 8) * 2;
        bf16x8 k0 = *(const bf16x8*)(lds + ((l16 * 256 + dby)        ^ ((l16 & 7) << 4)));
        bf16x8 k1 = *(const bf16x8*)(lds + (((l16 + 16) * 256 + dby) ^ ((l16 & 7) << 4)));
        s0 = __builtin_amdgcn_mfma_f32_16x16x32_bf16(qf[kb], k0, s0, 0, 0, 0);
        s1 = __builtin_amdgcn_mfma_f32_16x16x32_bf16(qf[kb], k1, s1, 0, 0, 0);
    }
    if (masked) {
        #pragma unroll
        for (int r = 0; r < 4; ++r) {
            const int qrel = qrel0 + lhi * 4 + r;
            if (cbase + l16 > qrel)      s0[r] = MASKVAL;
            if (cbase + 16 + l16 > qrel) s1[r] = MASKVAL;
        }
    }
    float pmax[4];
    #pragma unroll
    for (int r = 0; r < 4; ++r) pmax[r] = fmaxf(s0[r], s1[r]);
    #pragma unroll
    for (int off = 1; off < 16; off <<= 1) {
        #pragma unroll
        for (int r = 0; r < 4; ++r)
            pmax[r] = fmaxf(pmax[r], __shfl_xor(pmax[r], off));
    }
    f32x4 p0, p1;
    float alpha[4], rsum[4];
    #pragma unroll
    for (int r = 0; r < 4; ++r) {
        const float mnew = fmaxf(m_r[r], pmax[r]);
        alpha[r] = exp2f(m_r[r] - mnew);
        m_r[r]   = mnew;
        p0[r] = exp2f(s0[r] - mnew);
        p1[r] = exp2f(s1[r] - mnew);
        rsum[r] = p0[r] + p1[r];
    }
    #pragma unroll
    for (int off = 1; off < 16; off <<= 1) {
        #pragma unroll
        for (int r = 0; r < 4; ++r)
            rsum[r] += __shfl_xor(rsum[r], off);
    }
    #pragma unroll
    for (int r = 0; r < 4; ++r) l_r[r] = l_r[r] * alpha[r] + rsum[r];
    #pragma unroll
    for (int nb = 0; nb < 8; ++nb) {
        #pragma unroll
        for (int r = 0; r < 4; ++r) acc[nb][r] *= alpha[r];
    }
    #pragma unroll
    for (int r = 0; r < 4; ++r) {
        const int rq  = lhi * 4 + r;
        const int rsw = (rq & 7) << 4;
        *(__bf16*)(pbase + ((rq * 64 + l16 * 2)        ^ rsw)) = (__bf16)p0[r];
        *(__bf16*)(pbase + ((rq * 64 + (l16 + 16) * 2) ^ rsw)) = (__bf16)p1[r];
    }
    bf16x8 pa = *(const bf16x8*)(pbase + ((l16 * 64 + lhi * 16) ^ ((l16 & 7) << 4)));
    #pragma unroll
    for (int nb = 0; nb < 8; ++nb) {
        const int d = nb * 16 + l16;
        const int vsw = ((d & 7) ^ (nb & 7)) << 4;
        bf16x8 vb = *(const bf16x8*)(lds + 8192 + ((d * 64 + lhi * 16) ^ vsw));
        acc[nb] = __builtin_amdgcn_mfma_f32_16x16x32_bf16(pa, vb, acc[nb], 0, 0, 0);
    }
}

__global__ __launch_bounds__(256, 2)
void zz_attn_part_old(const float* __restrict__ qg, const float* __restrict__ kg,
                      const float* __restrict__ vg,
                      float* __restrict__ Op, float* __restrict__ mp, float* __restrict__ lp)
{
    __shared__ __align__(16) char lds[20480];
    const int bid = blockIdx.x;
    int half, part, q_tile, hkv;
    if (bid < 256) { half = 0; part = 0; q_tile = bid & 31; hkv = bid >> 5; }
    else { const int e = bid - 256; half = 1; part = e & 3;
           q_tile = 32 + ((e >> 2) & 31); hkv = e >> 7; }
    const int tid  = threadIdx.x;
    const int w    = tid >> 6;
    const int lane = tid & 63;
    const int l16  = lane & 15;
    const int lhi  = lane >> 4;
    const int h    = hkv * GRP + w;
    const int qr0  = q_tile << 4;
    const int qrel0 = (q_tile & 31) << 4;

    bf16x8 qf[4];
    load_qfrag(qg, qr0, h, l16, lhi, qf);
    f32x4 acc[8];
    #pragma unroll
    for (int i = 0; i < 8; ++i) acc[i] = f32x4{0.f, 0.f, 0.f, 0.f};
    float m_r[4], l_r[4];
    #pragma unroll
    for (int r = 0; r < 4; ++r) { m_r[r] = -1e30f; l_r[r] = 0.f; }
    char* const pbase = lds + 16384 + w * 1024;

    unsigned fullmask; int diag_slot;
    if (half == 0) { fullmask = 0x0015u; diag_slot = 6; }
    else {
        fullmask = (part == 0) ? 0x0015u : (part == 1) ? 0x0340u
                 : (part == 2) ? 0x1C00u : 0xE000u;
        diag_slot = (part == 3) ? 7 : -1;
    }
    #pragma unroll 1
    for (int s = 0; s < 16; ++s) {
        if (!((fullmask >> s) & 1)) continue;
        #pragma unroll 1
        for (int t = 0; t < 16; ++t)
            attn_tile_f32(lds, pbase, kg, vg, hkv, s * CHK + t * KB, 0, false,
                          tid, l16, lhi, qrel0, qf, acc, m_r, l_r);
    }
    if (diag_slot >= 0) {
        const int nd = (qrel0 >> 5) + 1;
        #pragma unroll 1
        for (int t = 0; t < nd; ++t)
            attn_tile_f32(lds, pbase, kg, vg, hkv, diag_slot * CHK + t * KB, t * KB, true,
                          tid, l16, lhi, qrel0, qf, acc, m_r, l_r);
    }
    float* op = Op + (size_t)part * (LQ * HQ * DH) + ((qr0 + lhi * 4) * HQ + h) * DH + l16;
    #pragma unroll
    for (int nb = 0; nb < 8; ++nb) {
        #pragma unroll
        for (int r = 0; r < 4; ++r)
            op[r * (HQ * DH) + nb * 16] = acc[nb][r];
    }
    if (l16 == 0) {
        #pragma unroll
        for (int r = 0; r < 4; ++r) {
            const int rh = (qr0 + lhi * 4 + r) * HQ + h;
            mp[part * RHN + rh] = m_r[r];
            lp[part * RHN + rh] = l_r[r];
            if (half == 0) {
                #pragma unroll
                for (int s = 1; s < NSPLIT; ++s) {
                    mp[s * RHN + rh] = -1e30f;
                    lp[s * RHN + rh] = 0.f;
                }
            }
        }
    }
}

extern "C" void kernel_launch(void* const* d_in, const int* in_sizes, int n_in,
                              void* d_out, int out_size, void* d_ws, size_t ws_size,
                              hipStream_t stream)
{
    (void)in_sizes; (void)n_in; (void)out_size;
    const float* q = (const float*)d_in[0];
    const float* k = (const float*)d_in[1];
    const float* v = (const float*)d_in[2];
    float* out = (float*)d_out;

    const size_t sz_op = (size_t)NSPLIT * LQ * HQ * DH * 4;   // 67.1 MB
    const size_t sz_ml = (size_t)NSPLIT * RHN * 4;            // 0.5 MB each
    const size_t sz_kv = (size_t)HKV * HKV_BYTES;             // 16.78 MB each
    const size_t need_split = sz_op + 2 * sz_ml;
    const size_t need_full  = need_split + 2 * sz_kv;

    float* Op = (float*)d_ws;
    float* mp = (float*)((char*)d_ws + sz_op);
    float* lp = (float*)((char*)d_ws + sz_op + sz_ml);

    if (ws_size >= need_full) {
        char* Kp = (char*)d_ws + need_split;
        char* Vp = Kp + sz_kv;
        hipLaunchKernelGGL(zz_prep,  dim3(2048), dim3(256), 0, stream, k, v, Kp, Vp);
        hipLaunchKernelGGL(zz_part2, dim3(1280), dim3(256), 0, stream, q, Kp, Vp, Op, mp, lp);
        hipLaunchKernelGGL(zz_combine, dim3((RHN * DH / 4) / 256), dim3(256), 0, stream,
                           Op, mp, lp, out);
    } else {
        hipLaunchKernelGGL(zz_attn_part_old, dim3(1280), dim3(256), 0, stream, q, k, v, Op, mp, lp);
        hipLaunchKernelGGL(zz_combine, dim3((RHN * DH / 4) / 256), dim3(256), 0, stream,
                           Op, mp, lp, out);
    }
}